// Round 1
// baseline (605.312 us; speedup 1.0000x reference)
//
#include <hip/hip_runtime.h>
#include <stdint.h>
#include <stddef.h>

// ---------------------------------------------------------------- types
typedef __attribute__((ext_vector_type(8))) short short8;
typedef __attribute__((ext_vector_type(4))) short short4v;
typedef __attribute__((ext_vector_type(4))) float floatx4;

#define DEV __device__ __forceinline__

DEV float bf2f(short s) {
    union { float f; uint32_t u; } v;
    v.u = ((uint32_t)(uint16_t)s) << 16;
    return v.f;
}
DEV short f2bf(float f) {
    union { float f; uint32_t u; } v;
    v.f = f;
    uint32_t u = v.u + 0x7FFFu + ((v.u >> 16) & 1u);  // RNE
    return (short)(u >> 16);
}

// ---------------------------------------------------------------- GEMM
// C(M,N) = A(M,K) @ Bt(N,K)^T ; A,Bt bf16 row-major, acc fp32.
// 128x128 tile, 4 waves (2x2 of 64x64), BK=32, global_load_lds width 16.
template<int BIAS, int RELU, int OUTBF>
__global__ __launch_bounds__(256) void gemm_bt(
    const short* __restrict__ A, const short* __restrict__ Bt,
    const float* __restrict__ bias, void* __restrict__ Cout,
    int M, int N, int K)
{
    __shared__ short Alds[128 * 32];   // [row][k], 64B rows, linear (gload_lds)
    __shared__ short Blds[128 * 32];
    const int tid  = threadIdx.x;
    const int wave = tid >> 6, lane = tid & 63;
    const int g = lane >> 4, li = lane & 15;
    const long bm = (long)blockIdx.x * 128;
    const long bn = (long)blockIdx.y * 128;
    const int wr = (wave >> 1) * 64;
    const int wc = (wave & 1) * 64;
    const short* Ap = A + bm * K;
    const short* Bp = Bt + bn * K;
    const int srow = wave * 32 + (lane >> 2);   // staging row within tile
    const int scol = (lane & 3) * 8;            // staging k-offset (elems)

    floatx4 acc[4][4];
#pragma unroll
    for (int i = 0; i < 4; i++)
#pragma unroll
        for (int j = 0; j < 4; j++) acc[i][j] = (floatx4){0.f, 0.f, 0.f, 0.f};

    for (int k0 = 0; k0 < K; k0 += 32) {
        __syncthreads();
        __builtin_amdgcn_global_load_lds(
            (const __attribute__((address_space(1))) void*)(Ap + (long)srow * K + k0 + scol),
            (__attribute__((address_space(3))) void*)(Alds + wave * 1024), 16, 0, 0);
        __builtin_amdgcn_global_load_lds(
            (const __attribute__((address_space(1))) void*)(Ap + (long)(srow + 16) * K + k0 + scol),
            (__attribute__((address_space(3))) void*)(Alds + wave * 1024 + 512), 16, 0, 0);
        __builtin_amdgcn_global_load_lds(
            (const __attribute__((address_space(1))) void*)(Bp + (long)srow * K + k0 + scol),
            (__attribute__((address_space(3))) void*)(Blds + wave * 1024), 16, 0, 0);
        __builtin_amdgcn_global_load_lds(
            (const __attribute__((address_space(1))) void*)(Bp + (long)(srow + 16) * K + k0 + scol),
            (__attribute__((address_space(3))) void*)(Blds + wave * 1024 + 512), 16, 0, 0);
        __syncthreads();

        short8 af[4], bfr[4];
#pragma unroll
        for (int mi = 0; mi < 4; mi++)
            af[mi] = *(const short8*)(Alds + (wr + mi * 16 + li) * 32 + g * 8);
#pragma unroll
        for (int ni = 0; ni < 4; ni++)
            bfr[ni] = *(const short8*)(Blds + (wc + ni * 16 + li) * 32 + g * 8);
#pragma unroll
        for (int mi = 0; mi < 4; mi++)
#pragma unroll
            for (int ni = 0; ni < 4; ni++)
                acc[mi][ni] = __builtin_amdgcn_mfma_f32_16x16x32_bf16(
                    af[mi], bfr[ni], acc[mi][ni], 0, 0, 0);
    }

    float* Cf = (float*)Cout;
    short* Cb = (short*)Cout;
#pragma unroll
    for (int mi = 0; mi < 4; mi++) {
#pragma unroll
        for (int ni = 0; ni < 4; ni++) {
            const long col = bn + wc + ni * 16 + li;
            const float bv = BIAS ? bias[col] : 0.f;
#pragma unroll
            for (int i = 0; i < 4; i++) {
                const long row = bm + wr + mi * 16 + g * 4 + i;
                float v = acc[mi][ni][i] + bv;
                if (RELU) v = fmaxf(v, 0.f);
                if (OUTBF) Cb[row * N + col] = f2bf(v);
                else       Cf[row * N + col] = v;
            }
        }
    }
}

// ---------------------------------------------------------------- attention
// Q:(B,NQ,512) bf16, K:(B,NK,512) bf16, VT:(B,512,NK) bf16 -> O:(B,NQ,512) bf16
// block = 4 waves, each wave owns 16 q-rows. KT=32 keys/iter.
// Swapped QK^T (mfma(K,Q)) and swapped PV (mfma(VT,P)) keep q = lane&15.
__global__ __launch_bounds__(256) void attn_kernel(
    const short* __restrict__ Qg, const short* __restrict__ Kg,
    const short* __restrict__ VTg, short* __restrict__ Og,
    int NQ, int NK)
{
    __shared__ short Klds[32 * 72];       // [key][d], stride 72 (pad 8)
    __shared__ short Vlds[64 * 40];       // [d][key], stride 40 (pad 8)
    __shared__ short Plds[4][16 * 40];    // per-wave [q][key], stride 40

    const int tid = threadIdx.x;
    const int wave = tid >> 6, lane = tid & 63;
    const int g = lane >> 4, li = lane & 15;
    const int b = blockIdx.z, h = blockIdx.y;
    const int q0 = blockIdx.x * 64 + wave * 16;

    // Q fragments (B-operand): lane holds Q[q=li][d = f*32 + 8g + i], scaled by 1/8
    const short* qptr = Qg + ((long)(b * NQ + q0 + li) * 512 + h * 64);
    short8 qf[2];
#pragma unroll
    for (int f = 0; f < 2; f++) {
        short8 t = *(const short8*)(qptr + f * 32 + g * 8);
#pragma unroll
        for (int i = 0; i < 8; i++) t[i] = f2bf(bf2f(t[i]) * 0.125f);
        qf[f] = t;
    }

    floatx4 acc[4];
#pragma unroll
    for (int s = 0; s < 4; s++) acc[s] = (floatx4){0.f, 0.f, 0.f, 0.f};
    float m = -1e30f, lsum = 0.f;

    const short* kbase = Kg + (long)b * NK * 512 + h * 64;
    const short* vbase = VTg + ((long)(b * 512 + h * 64)) * NK;
    const int skey = tid >> 3, sdc = (tid & 7) * 8;  // K staging: 32 keys x 64 d
    const int svd = tid >> 2, svk = (tid & 3) * 8;   // VT staging: 64 d x 32 keys

    for (int kt = 0; kt < NK; kt += 32) {
        __syncthreads();
        *(short8*)(Klds + skey * 72 + sdc) =
            *(const short8*)(kbase + (long)(kt + skey) * 512 + sdc);
        *(short8*)(Vlds + svd * 40 + svk) =
            *(const short8*)(vbase + (long)svd * NK + kt + svk);
        __syncthreads();

        // S^T = K_tile(32x64) . Q^T(64x16): lane holds S[key=sub*16+4g+i][q=li]
        floatx4 sT0 = (floatx4){0.f, 0.f, 0.f, 0.f};
        floatx4 sT1 = (floatx4){0.f, 0.f, 0.f, 0.f};
        {
            short8 k00 = *(const short8*)(Klds + li * 72 + g * 8);
            short8 k01 = *(const short8*)(Klds + li * 72 + 32 + g * 8);
            short8 k10 = *(const short8*)(Klds + (16 + li) * 72 + g * 8);
            short8 k11 = *(const short8*)(Klds + (16 + li) * 72 + 32 + g * 8);
            sT0 = __builtin_amdgcn_mfma_f32_16x16x32_bf16(k00, qf[0], sT0, 0, 0, 0);
            sT0 = __builtin_amdgcn_mfma_f32_16x16x32_bf16(k01, qf[1], sT0, 0, 0, 0);
            sT1 = __builtin_amdgcn_mfma_f32_16x16x32_bf16(k10, qf[0], sT1, 0, 0, 0);
            sT1 = __builtin_amdgcn_mfma_f32_16x16x32_bf16(k11, qf[1], sT1, 0, 0, 0);
        }

        // online softmax (row = q = li; 4 lanes per q-group: xor 16,32)
        float mt = fmaxf(fmaxf(fmaxf(sT0[0], sT0[1]), fmaxf(sT0[2], sT0[3])),
                         fmaxf(fmaxf(sT1[0], sT1[1]), fmaxf(sT1[2], sT1[3])));
        mt = fmaxf(mt, __shfl_xor(mt, 16));
        mt = fmaxf(mt, __shfl_xor(mt, 32));
        const float mnew = fmaxf(m, mt);
        const float corr = exp2f((m - mnew) * 1.44269504f);
        m = mnew;
        float p[8];
#pragma unroll
        for (int i = 0; i < 4; i++) p[i]     = exp2f((sT0[i] - mnew) * 1.44269504f);
#pragma unroll
        for (int i = 0; i < 4; i++) p[4 + i] = exp2f((sT1[i] - mnew) * 1.44269504f);
        lsum = lsum * corr + (p[0] + p[1] + p[2] + p[3] + p[4] + p[5] + p[6] + p[7]);
#pragma unroll
        for (int s = 0; s < 4; s++) {
            acc[s][0] *= corr; acc[s][1] *= corr; acc[s][2] *= corr; acc[s][3] *= corr;
        }

        // P (bf16) -> LDS in [q][key] layout for B-fragment read
        short4v pw0 = { f2bf(p[0]), f2bf(p[1]), f2bf(p[2]), f2bf(p[3]) };
        short4v pw1 = { f2bf(p[4]), f2bf(p[5]), f2bf(p[6]), f2bf(p[7]) };
        *(short4v*)(Plds[wave] + li * 40 + g * 4) = pw0;
        *(short4v*)(Plds[wave] + li * 40 + 16 + g * 4) = pw1;
        short8 pf = *(const short8*)(Plds[wave] + li * 40 + g * 8);

        // O^T slices: acc[s] += VT_slice(16d x 32k) . P^T(32k x 16q)
#pragma unroll
        for (int s = 0; s < 4; s++) {
            short8 vf = *(const short8*)(Vlds + (s * 16 + li) * 40 + g * 8);
            acc[s] = __builtin_amdgcn_mfma_f32_16x16x32_bf16(vf, pf, acc[s], 0, 0, 0);
        }
    }

    lsum += __shfl_xor(lsum, 16);
    lsum += __shfl_xor(lsum, 32);
    const float inv = 1.f / lsum;
    short* optr = Og + ((long)(b * NQ + q0 + li) * 512 + h * 64);
#pragma unroll
    for (int s = 0; s < 4; s++) {
        short4v o4 = { f2bf(acc[s][0] * inv), f2bf(acc[s][1] * inv),
                       f2bf(acc[s][2] * inv), f2bf(acc[s][3] * inv) };
        *(short4v*)(optr + s * 16 + g * 4) = o4;  // d = s*16 + 4g + i
    }
}

// ---------------------------------------------------------------- small kernels
// out_f32 (opt) and out_bf16 = a (+ b opt)
__global__ __launch_bounds__(256) void add_conv(
    const float* __restrict__ a, const float* __restrict__ b,
    float* __restrict__ of, short* __restrict__ ob)
{
    const long i = (long)(blockIdx.x * 256 + threadIdx.x) * 4;
    float4 va = *(const float4*)(a + i);
    if (b) {
        const float4 vb = *(const float4*)(b + i);
        va.x += vb.x; va.y += vb.y; va.z += vb.z; va.w += vb.w;
    }
    if (of) *(float4*)(of + i) = va;
    short4v o = { f2bf(va.x), f2bf(va.y), f2bf(va.z), f2bf(va.w) };
    *(short4v*)(ob + i) = o;
}

// LayerNorm(512) * g + b + res -> fp32 (+ bf16 opt). 1 wave / row.
__global__ __launch_bounds__(256) void ln_res_kernel(
    const float* __restrict__ X, const float* __restrict__ gam,
    const float* __restrict__ bet, const float* __restrict__ res,
    float* __restrict__ outF, short* __restrict__ outB)
{
    const int row = blockIdx.x * 4 + (threadIdx.x >> 6);
    const int lane = threadIdx.x & 63;
    const long base = (long)row * 512 + lane * 8;
    float x[8];
    *(float4*)(x) = *(const float4*)(X + base);
    *(float4*)(x + 4) = *(const float4*)(X + base + 4);
    float s = x[0] + x[1] + x[2] + x[3] + x[4] + x[5] + x[6] + x[7];
#pragma unroll
    for (int o = 1; o < 64; o <<= 1) s += __shfl_xor(s, o);
    const float mu = s * (1.0f / 512.0f);
    float vs = 0.f;
#pragma unroll
    for (int i = 0; i < 8; i++) { const float d = x[i] - mu; vs += d * d; }
#pragma unroll
    for (int o = 1; o < 64; o <<= 1) vs += __shfl_xor(vs, o);
    const float rs = rsqrtf(vs * (1.0f / 512.0f) + 1e-5f);

    float gv[8], bv[8], rv[8];
    *(float4*)(gv) = *(const float4*)(gam + lane * 8);
    *(float4*)(gv + 4) = *(const float4*)(gam + lane * 8 + 4);
    *(float4*)(bv) = *(const float4*)(bet + lane * 8);
    *(float4*)(bv + 4) = *(const float4*)(bet + lane * 8 + 4);
    *(float4*)(rv) = *(const float4*)(res + base);
    *(float4*)(rv + 4) = *(const float4*)(res + base + 4);

    float y[8];
#pragma unroll
    for (int i = 0; i < 8; i++) y[i] = (x[i] - mu) * rs * gv[i] + bv[i] + rv[i];
    *(float4*)(outF + base) = *(float4*)(y);
    *(float4*)(outF + base + 4) = *(float4*)(y + 4);
    if (outB) {
        short8 ob;
#pragma unroll
        for (int i = 0; i < 8; i++) ob[i] = f2bf(y[i]);
        *(short8*)(outB + base) = ob;
    }
}

// W (K,N) f32 -> Wt (N,K) bf16
__global__ __launch_bounds__(256) void wtrans(
    const float* __restrict__ W, short* __restrict__ Wt, int K, int N)
{
    __shared__ short t[32][33];
    const int n0 = blockIdx.x * 32, k0 = blockIdx.y * 32;
    const int tx = threadIdx.x & 31, ty = threadIdx.x >> 5;
    for (int r = ty; r < 32; r += 8)
        t[r][tx] = f2bf(W[(long)(k0 + r) * N + n0 + tx]);
    __syncthreads();
    for (int r = ty; r < 32; r += 8)
        Wt[(long)(n0 + r) * K + k0 + tx] = t[tx][r];
}

// V (B,NK,512) bf16 -> VT (B,512,NK) bf16
__global__ __launch_bounds__(256) void vtrans(
    const short* __restrict__ V, short* __restrict__ VT, int NK)
{
    __shared__ short t[32][33];
    const int b = blockIdx.z;
    const int key0 = blockIdx.x * 32, c0 = blockIdx.y * 32;
    const int tx = threadIdx.x & 31, ty = threadIdx.x >> 5;
    for (int r = ty; r < 32; r += 8)
        t[r][tx] = V[((long)b * NK + key0 + r) * 512 + c0 + tx];
    __syncthreads();
    for (int r = ty; r < 32; r += 8)
        VT[((long)b * 512 + c0 + r) * NK + key0 + tx] = t[tx][r];
}

// ---------------------------------------------------------------- launch
extern "C" void kernel_launch(void* const* d_in, const int* in_sizes, int n_in,
                              void* d_out, int out_size, void* d_ws, size_t ws_size,
                              hipStream_t stream)
{
    (void)in_sizes; (void)n_in; (void)out_size; (void)ws_size;
    const float* tgt   = (const float*)d_in[0];
    const float* mem   = (const float*)d_in[1];
    const float* pos   = (const float*)d_in[2];
    const float* qpos  = (const float*)d_in[3];
    const float* a0_wq = (const float*)d_in[4];
    const float* a0_wk = (const float*)d_in[5];
    const float* a0_wv = (const float*)d_in[6];
    const float* a0_wo = (const float*)d_in[7];
    const float* a0_bo = (const float*)d_in[8];
    const float* a0_g  = (const float*)d_in[9];
    const float* a0_b  = (const float*)d_in[10];
    const float* f0_w1 = (const float*)d_in[11];
    const float* f0_b1 = (const float*)d_in[12];
    const float* f0_w2 = (const float*)d_in[13];
    const float* f0_b2 = (const float*)d_in[14];
    const float* f0_g  = (const float*)d_in[15];
    const float* f0_b  = (const float*)d_in[16];
    const float* a1_wq = (const float*)d_in[17];
    const float* a1_wk = (const float*)d_in[18];
    const float* a1_wv = (const float*)d_in[19];
    const float* a1_wo = (const float*)d_in[20];
    const float* a1_bo = (const float*)d_in[21];
    const float* a1_g  = (const float*)d_in[22];
    const float* a1_b  = (const float*)d_in[23];
    const float* f1_w1 = (const float*)d_in[24];
    const float* f1_b1 = (const float*)d_in[25];
    const float* f1_w2 = (const float*)d_in[26];
    const float* f1_b2 = (const float*)d_in[27];
    const float* f1_g  = (const float*)d_in[28];
    const float* f1_b  = (const float*)d_in[29];

    const int M1 = 8 * 1024;   // 8192 query rows
    const int M2 = 8 * 2048;   // 16384 memory rows
    const size_t MB = 1ull << 20;
    char* ws = (char*)d_ws;

    float* resid = (float*)(ws + 0 * MB);       // 16MB: q0 / qc residual
    float* xf    = (float*)(ws + 16 * MB);      // 16MB: current activation f32
    short* xb    = (short*)(ws + 32 * MB);      // 8MB:  current activation bf16
    short* wb    = (short*)(ws + 40 * MB);      // 12MB: bf16 W^T bank
    short* a0_wqt = wb;            short* a0_wkt = wb + 262144;
    short* a0_wvt = wb + 524288;   short* a0_wot = wb + 786432;
    short* f0_w1t = wb + 1048576;  short* f0_w2t = wb + 2097152;
    short* a1_wqt = wb + 3145728;  short* a1_wkt = wb + 3407872;
    short* a1_wvt = wb + 3670016;  short* a1_wot = wb + 3932160;
    short* f1_w1t = wb + 4194304;  short* f1_w2t = wb + 5242880;
    char* S = ws + 56 * MB;                      // stage scratch (120MB max)

    // weight transposes (f32 -> bf16 W^T)
    wtrans<<<dim3(16, 16), 256, 0, stream>>>(a0_wq, a0_wqt, 512, 512);
    wtrans<<<dim3(16, 16), 256, 0, stream>>>(a0_wk, a0_wkt, 512, 512);
    wtrans<<<dim3(16, 16), 256, 0, stream>>>(a0_wv, a0_wvt, 512, 512);
    wtrans<<<dim3(16, 16), 256, 0, stream>>>(a0_wo, a0_wot, 512, 512);
    wtrans<<<dim3(64, 16), 256, 0, stream>>>(f0_w1, f0_w1t, 512, 2048);
    wtrans<<<dim3(16, 64), 256, 0, stream>>>(f0_w2, f0_w2t, 2048, 512);
    wtrans<<<dim3(16, 16), 256, 0, stream>>>(a1_wq, a1_wqt, 512, 512);
    wtrans<<<dim3(16, 16), 256, 0, stream>>>(a1_wk, a1_wkt, 512, 512);
    wtrans<<<dim3(16, 16), 256, 0, stream>>>(a1_wv, a1_wvt, 512, 512);
    wtrans<<<dim3(16, 16), 256, 0, stream>>>(a1_wo, a1_wot, 512, 512);
    wtrans<<<dim3(64, 16), 256, 0, stream>>>(f1_w1, f1_w1t, 512, 2048);
    wtrans<<<dim3(16, 64), 256, 0, stream>>>(f1_w2, f1_w2t, 2048, 512);

    // ---------------- block A0: self-attention ----------------
    short* Qs   = (short*)(S + 0 * MB);
    short* Ks   = (short*)(S + 8 * MB);
    short* Vs   = (short*)(S + 16 * MB);
    short* VsT  = (short*)(S + 24 * MB);
    short* AOs  = (short*)(S + 32 * MB);
    float* Of   = (float*)(S + 40 * MB);
    short* q0b  = (short*)(S + 56 * MB);
    short* tgtb = (short*)(S + 64 * MB);

    add_conv<<<4096, 256, 0, stream>>>(tgt, qpos, resid, q0b);       // q0 = tgt+qpos
    add_conv<<<4096, 256, 0, stream>>>(tgt, nullptr, nullptr, tgtb); // tgt bf16

    gemm_bt<0,0,1><<<dim3(64, 4), 256, 0, stream>>>(q0b,  a0_wqt, nullptr, Qs, M1, 512, 512);
    gemm_bt<0,0,1><<<dim3(64, 4), 256, 0, stream>>>(q0b,  a0_wkt, nullptr, Ks, M1, 512, 512);
    gemm_bt<0,0,1><<<dim3(64, 4), 256, 0, stream>>>(tgtb, a0_wvt, nullptr, Vs, M1, 512, 512);
    vtrans<<<dim3(32, 16, 8), 256, 0, stream>>>(Vs, VsT, 1024);
    attn_kernel<<<dim3(16, 8, 8), 256, 0, stream>>>(Qs, Ks, VsT, AOs, 1024, 1024);
    gemm_bt<1,0,0><<<dim3(64, 4), 256, 0, stream>>>(AOs, a0_wot, a0_bo, Of, M1, 512, 512);
    ln_res_kernel<<<2048, 256, 0, stream>>>(Of, a0_g, a0_b, resid, xf, xb);

    // ---------------- block F0: FFN ----------------
    short* Hb  = (short*)(S + 0 * MB);     // 32MB
    float* O2f = (float*)(S + 32 * MB);    // 16MB
    gemm_bt<1,1,1><<<dim3(64, 16), 256, 0, stream>>>(xb, f0_w1t, f0_b1, Hb, M1, 2048, 512);
    gemm_bt<1,0,0><<<dim3(64, 4), 256, 0, stream>>>(Hb, f0_w2t, f0_b2, O2f, M1, 512, 2048);
    ln_res_kernel<<<2048, 256, 0, stream>>>(O2f, f0_g, f0_b, xf, xf, xb);

    // ---------------- block A1: cross-attention ----------------
    short* Qc   = (short*)(S + 0 * MB);
    short* Kc   = (short*)(S + 8 * MB);
    short* Vc   = (short*)(S + 24 * MB);
    short* VcT  = (short*)(S + 40 * MB);
    short* AOc  = (short*)(S + 56 * MB);
    float* Ocf  = (float*)(S + 64 * MB);
    short* qcb  = (short*)(S + 80 * MB);
    short* kcb  = (short*)(S + 88 * MB);
    short* memb = (short*)(S + 104 * MB);

    add_conv<<<4096, 256, 0, stream>>>(xf, qpos, resid, qcb);         // qc = x + qpos
    add_conv<<<8192, 256, 0, stream>>>(mem, pos, nullptr, kcb);       // kc = mem + pos
    add_conv<<<8192, 256, 0, stream>>>(mem, nullptr, nullptr, memb);  // mem bf16

    gemm_bt<0,0,1><<<dim3(64, 4), 256, 0, stream>>>(qcb,  a1_wqt, nullptr, Qc, M1, 512, 512);
    gemm_bt<0,0,1><<<dim3(128, 4), 256, 0, stream>>>(kcb,  a1_wkt, nullptr, Kc, M2, 512, 512);
    gemm_bt<0,0,1><<<dim3(128, 4), 256, 0, stream>>>(memb, a1_wvt, nullptr, Vc, M2, 512, 512);
    vtrans<<<dim3(64, 16, 8), 256, 0, stream>>>(Vc, VcT, 2048);
    attn_kernel<<<dim3(16, 8, 8), 256, 0, stream>>>(Qc, Kc, VcT, AOc, 1024, 2048);
    gemm_bt<1,0,0><<<dim3(64, 4), 256, 0, stream>>>(AOc, a1_wot, a1_bo, Ocf, M1, 512, 512);
    ln_res_kernel<<<2048, 256, 0, stream>>>(Ocf, a1_g, a1_b, resid, xf, xb);

    // ---------------- block F1: FFN (writes d_out) ----------------
    short* Hb2  = (short*)(S + 0 * MB);
    float* O3f  = (float*)(S + 32 * MB);
    gemm_bt<1,1,1><<<dim3(64, 16), 256, 0, stream>>>(xb, f1_w1t, f1_b1, Hb2, M1, 2048, 512);
    gemm_bt<1,0,0><<<dim3(64, 4), 256, 0, stream>>>(Hb2, f1_w2t, f1_b2, O3f, M1, 512, 2048);
    ln_res_kernel<<<2048, 256, 0, stream>>>(O3f, f1_g, f1_b, xf, (float*)d_out, nullptr);
}